// Round 8
// baseline (86.124 us; speedup 1.0000x reference)
//
#include <hip/hip_runtime.h>
#include <hip/hip_bf16.h>

typedef _Float16 half8 __attribute__((ext_vector_type(8)));
typedef _Float16 half4 __attribute__((ext_vector_type(4)));
typedef _Float16 half2v __attribute__((ext_vector_type(2)));
typedef float    f32x4 __attribute__((ext_vector_type(4)));

constexpr int Bb = 1024;
constexpr int TS = 512;   // 8 waves, 2 M-tiles per wave

// ---- workspace byte offsets ----
constexpr int W_WEV  = 0;        // f32 [64][256]  Wev[d][h]   (pre1 -> pre2 only)
constexpr int W_MTH  = 65536;    // f16 [64][256]  Mt[d][s]
constexpr int W_WEKH = 98304;    // f16 [64][64]   WekT[k][d]
constexpr int W_WEQH = 106496;   // f16 [64][64]   WeqT[k][d]
constexpr int W_BEQ  = 114688;   // f32[64]
constexpr int W_BEV  = 114944;   // f32[256]
constexpr int W_CS   = 115968;   // f32[256]
constexpr int W_CB   = 116992;   // f32[256]
constexpr int W_MS   = 118016;   // f32[64]
constexpr int W_C0   = 118272;   // f32[1]

__global__ void pre1_kernel(const float* __restrict__ W_emb, const float* __restrict__ b_emb,
                            const float* __restrict__ W_k,   const float* __restrict__ W_q,
                            const float* __restrict__ b_q,   const float* __restrict__ W_v,
                            const float* __restrict__ b_v,   const float* __restrict__ W_d,
                            char* __restrict__ wsb) {
  int i = blockIdx.x * blockDim.x + threadIdx.x;
  if (i < 16384) {                       // Wev[d][h]
    int d = i >> 8, h = i & 255;
    float a = 0.f;
#pragma unroll 8
    for (int hp = 0; hp < 256; ++hp) a += W_emb[d*256 + hp] * W_v[hp*256 + h];
    ((float*)(wsb + W_WEV))[i] = a;
  } else if (i < 20480) {                // WekT[k][d]
    int j = i - 16384; int k = j & 63, d = j >> 6;
    float a = 0.f;
#pragma unroll 8
    for (int h = 0; h < 256; ++h) a += W_emb[d*256 + h] * W_k[h*64 + k];
    ((_Float16*)(wsb + W_WEKH))[k*64 + d] = (_Float16)a;
  } else if (i < 24576) {                // WeqT[k][d]
    int j = i - 20480; int k = j & 63, d = j >> 6;
    float a = 0.f;
#pragma unroll 8
    for (int h = 0; h < 256; ++h) a += W_emb[d*256 + h] * W_q[h*64 + k];
    ((_Float16*)(wsb + W_WEQH))[k*64 + d] = (_Float16)a;
  } else if (i < 24640) {                // beq[k]
    int k = i - 24576;
    float a = b_q[k];
    for (int h = 0; h < 256; ++h) a += b_emb[h] * W_q[h*64 + k];
    ((float*)(wsb + W_BEQ))[k] = a;
  } else if (i < 24896) {                // bev[h]
    int h = i - 24640;
    float a = b_v[h];
    for (int hp = 0; hp < 256; ++hp) a += b_emb[hp] * W_v[hp*256 + h];
    ((float*)(wsb + W_BEV))[h] = a;
  } else if (i < 25152) {                // cs[h]
    int h = i - 24896;
    float a = 0.f;
    for (int s = 0; s < 256; ++s) a += W_d[s*256 + h];
    ((float*)(wsb + W_CS))[h] = a;
  }
}

__global__ void pre2_kernel(const float* __restrict__ W_d, const float* __restrict__ b_d,
                            char* __restrict__ wsb) {
  int i = blockIdx.x * blockDim.x + threadIdx.x;
  const float* wev = (const float*)(wsb + W_WEV);
  if (i < 16384) {                       // Mt[d][s] = sum_h W_d[s,h]*Wev[d,h]
    int d = i >> 8, s = i & 255;
    float a = 0.f;
#pragma unroll 8
    for (int h = 0; h < 256; ++h) a += W_d[s*256 + h] * wev[d*256 + h];
    ((_Float16*)(wsb + W_MTH))[i] = (_Float16)a;
  } else if (i < 16640) {                // cb[s]
    int s = i - 16384;
    const float* bev = (const float*)(wsb + W_BEV);
    float a = 0.f;
    for (int h = 0; h < 256; ++h) a += W_d[s*256 + h] * bev[h];
    ((float*)(wsb + W_CB))[s] = a;
  } else if (i < 16704) {                // ms[d]
    int d = i - 16640;
    const float* cs = (const float*)(wsb + W_CS);
    float a = 0.f;
    for (int h = 0; h < 256; ++h) a += wev[d*256 + h] * cs[h];
    ((float*)(wsb + W_MS))[d] = a;
  } else if (i == 16704) {               // c0
    const float* cs  = (const float*)(wsb + W_CS);
    const float* bev = (const float*)(wsb + W_BEV);
    const float* beq = (const float*)(wsb + W_BEQ);
    float cbsum = 0.f;
    for (int h = 0; h < 256; ++h) cbsum += cs[h] * bev[h];
    float bqsum = 0.f;
    for (int k = 0; k < 64; ++k) bqsum += beq[k];
    ((float*)(wsb + W_C0))[0] = b_d[0] + cbsum * bqsum;
  }
}

// LDS byte-address helpers (G4 XOR swizzle)
__device__ __forceinline__ int adrR(int r, int c) {   // QT [64][256] f16 at 0, rows 512B
  return (((r << 9) + (c << 1)) ^ ((r & 7) << 4));
}
__device__ __forceinline__ int adrU(int k, int d) {   // U  [64][64]  f16 at 32768, rows 128B
  return 32768 + (((k << 7) + (d << 1)) ^ ((k & 7) << 4));
}

#define MFMA16(A, B, C) __builtin_amdgcn_mfma_f32_16x16x32_f16((A), (B), (C), 0, 0, 0)

// One block per batch, 8 waves, wave w owns s-rows 32w..32w+31 (2 row-tiles).
// LDS: QT 32K | U 8K | scr floats at 40960: [0,512) colsum partials (col*8+w), [512,520) wave acc
__global__ __launch_bounds__(TS, 6) void main_kernel(const float* __restrict__ inp_g,
                                                     const char* __restrict__ wsb,
                                                     float* __restrict__ out) {
  __shared__ __align__(16) char smem[43136];
  float* scrf = (float*)(smem + 40960);

  const int b = blockIdx.x, t = threadIdx.x;
  const int l = t & 63, w = t >> 6;            // w = 0..7
  const int lhi = l >> 4, llo = l & 15;

  const float* inp = inp_g + (size_t)b * 16384;

  // ---- A-fragments of inp straight from global (used in Phase B AND Phase E) ----
  half8 Af[4];   // [tl*2+ks]: rows w*32+llo (+16*tl), d = ks*32 + lhi*8 .. +8
  {
    const int srA = w * 32 + llo;
#pragma unroll
    for (int tl = 0; tl < 2; ++tl)
#pragma unroll
      for (int ks = 0; ks < 2; ++ks) {
        const float4* p = (const float4*)(inp + (srA + tl * 16) * 64 + ks * 32 + lhi * 8);
        float4 v0 = p[0], v1 = p[1];
        half8 h;
        h[0] = (_Float16)v0.x; h[1] = (_Float16)v0.y; h[2] = (_Float16)v0.z; h[3] = (_Float16)v0.w;
        h[4] = (_Float16)v1.x; h[5] = (_Float16)v1.y; h[6] = (_Float16)v1.z; h[7] = (_Float16)v1.w;
        Af[tl * 2 + ks] = h;
      }
  }

  f32x4 zero4 = {0.f, 0.f, 0.f, 0.f};
  float acc = 0.f;
  half2v ep[2][4][2];   // packed exp(logits), C-frag coords [tl][n][(r0,r1),(r2,r3)]

  // ---- Pass 1: logits = inp @ Wek; exp (no max: bias cancels, |logit| small); colsum partials ----
  {
    f32x4 clg[2][4];
#pragma unroll
    for (int tl = 0; tl < 2; ++tl)
#pragma unroll
      for (int n = 0; n < 4; ++n) clg[tl][n] = zero4;
    const _Float16* wekh = (const _Float16*)(wsb + W_WEKH);
#pragma unroll
    for (int ks = 0; ks < 2; ++ks) {
      const int kd = ks * 32 + lhi * 8;
      half8 Bk[4];
#pragma unroll
      for (int n = 0; n < 4; ++n) Bk[n] = *(const half8*)(wekh + (n * 16 + llo) * 64 + kd);
#pragma unroll
      for (int n = 0; n < 4; ++n) {
        clg[0][n] = MFMA16(Af[ks],     Bk[n], clg[0][n]);
        clg[1][n] = MFMA16(Af[2 + ks], Bk[n], clg[1][n]);
      }
    }
#pragma unroll
    for (int n = 0; n < 4; ++n) {
      float sum = 0.f;
      float ev[2][4];
#pragma unroll
      for (int tl = 0; tl < 2; ++tl)
#pragma unroll
        for (int r = 0; r < 4; ++r) { ev[tl][r] = __expf(clg[tl][n][r]); sum += ev[tl][r]; }
#pragma unroll
      for (int tl = 0; tl < 2; ++tl) {
        half2v p0, p1;
        p0[0] = (_Float16)ev[tl][0]; p0[1] = (_Float16)ev[tl][1];
        p1[0] = (_Float16)ev[tl][2]; p1[1] = (_Float16)ev[tl][3];
        ep[tl][n][0] = p0; ep[tl][n][1] = p1;
      }
      sum += __shfl_xor(sum, 16);
      sum += __shfl_xor(sum, 32);
      if (lhi == 0) scrf[(n * 16 + llo) * 8 + w] = sum;
    }
  }

  // ---- Pass 2: Q = inp @ Weq -> QT (f16, LDS) + cb-term (kills cq) ----
  {
    f32x4 cq[2][4];
#pragma unroll
    for (int tl = 0; tl < 2; ++tl)
#pragma unroll
      for (int n = 0; n < 4; ++n) cq[tl][n] = zero4;
    const _Float16* weqh = (const _Float16*)(wsb + W_WEQH);
#pragma unroll
    for (int ks = 0; ks < 2; ++ks) {
      const int kd = ks * 32 + lhi * 8;
      half8 Bq[4];
#pragma unroll
      for (int n = 0; n < 4; ++n) Bq[n] = *(const half8*)(weqh + (n * 16 + llo) * 64 + kd);
#pragma unroll
      for (int n = 0; n < 4; ++n) {
        cq[0][n] = MFMA16(Af[ks],     Bq[n], cq[0][n]);
        cq[1][n] = MFMA16(Af[2 + ks], Bq[n], cq[1][n]);
      }
    }
#pragma unroll
    for (int tl = 0; tl < 2; ++tl) {
      int sbase = w * 32 + tl * 16 + lhi * 4;
#pragma unroll
      for (int n = 0; n < 4; ++n) {
        half4 qh;
#pragma unroll
        for (int r = 0; r < 4; ++r) qh[r] = (_Float16)cq[tl][n][r];
        *(half4*)(smem + adrR(n * 16 + llo, sbase)) = qh;
      }
    }
    const float* cb = (const float*)(wsb + W_CB);
#pragma unroll
    for (int tl = 0; tl < 2; ++tl)
#pragma unroll
      for (int r = 0; r < 4; ++r) {
        float qs = (cq[tl][0][r] + cq[tl][1][r]) + (cq[tl][2][r] + cq[tl][3][r]);
        acc += cb[w * 32 + tl * 16 + lhi * 4 + r] * qs;
      }
  }

  // ---- Mt prefetch for Phase D (after cq freed) ----
  const int d0 = (w & 3) * 16;
  const int ka = (w >> 2) * 16, kb = ka + 32;
  half8 Bm[8];
  {
    const _Float16* mth = (const _Float16*)(wsb + W_MTH);
#pragma unroll
    for (int j = 0; j < 8; ++j)
      Bm[j] = *(const half8*)(mth + (d0 + llo) * 256 + j * 32 + lhi * 8);
  }
  __syncthreads();   // bar 1: QT + colsum partials visible

  // ---- Phase D: T = QT x Mt (K=256); U[k][d] = T + beq[k]*ms[d] -> LDS f16 ----
  {
    f32x4 cta = zero4, ctb = zero4;
#pragma unroll
    for (int ks = 0; ks < 8; ++ks) {
      const int kd = ks * 32 + lhi * 8;
      half8 Aqa = *(const half8*)(smem + adrR(ka + llo, kd));
      half8 Aqb = *(const half8*)(smem + adrR(kb + llo, kd));
      cta = MFMA16(Aqa, Bm[ks], cta);
      ctb = MFMA16(Aqb, Bm[ks], ctb);
    }
    const float* beq = (const float*)(wsb + W_BEQ);
    const float* msv = (const float*)(wsb + W_MS);
    float msd = msv[d0 + llo];
#pragma unroll
    for (int r = 0; r < 4; ++r) {
      float Uva = cta[r] + beq[ka + lhi * 4 + r] * msd;
      *(_Float16*)(smem + adrU(ka + lhi * 4 + r, d0 + llo)) = (_Float16)Uva;
      float Uvb = ctb[r] + beq[kb + lhi * 4 + r] * msd;
      *(_Float16*)(smem + adrU(kb + lhi * 4 + r, d0 + llo)) = (_Float16)Uvb;
    }
  }
  __syncthreads();   // bar 2: U visible

  // ---- Phase E: G = inp @ U^T (reuses Af); acc += sum e*cg / colsum ----
  {
    f32x4 cga[4], cgb[4];
#pragma unroll
    for (int n = 0; n < 4; ++n) { cga[n] = zero4; cgb[n] = zero4; }
#pragma unroll
    for (int ks = 0; ks < 2; ++ks) {
      const int kd = ks * 32 + lhi * 8;
      half8 Bu[4];
#pragma unroll
      for (int n = 0; n < 4; ++n) Bu[n] = *(const half8*)(smem + adrU(n * 16 + llo, kd));
#pragma unroll
      for (int n = 0; n < 4; ++n) {
        cga[n] = MFMA16(Af[ks],     Bu[n], cga[n]);
        cgb[n] = MFMA16(Af[2 + ks], Bu[n], cgb[n]);
      }
    }
#pragma unroll
    for (int n = 0; n < 4; ++n) {
      const float4* cp = (const float4*)(scrf + (n * 16 + llo) * 8);
      float4 c0v = cp[0], c1v = cp[1];
      float ss = ((c0v.x + c0v.y) + (c0v.z + c0v.w)) + ((c1v.x + c1v.y) + (c1v.z + c1v.w));
      float rs = __builtin_amdgcn_rcpf(ss);
      float dot = 0.f;
#pragma unroll
      for (int r = 0; r < 4; ++r) {
        float ea = (float)ep[0][n][r >> 1][r & 1];
        float eb = (float)ep[1][n][r >> 1][r & 1];
        dot += ea * cga[n][r] + eb * cgb[n][r];
      }
      acc += dot * rs;
    }
  }

  // ---- block reduction ----
#pragma unroll
  for (int off = 32; off; off >>= 1) acc += __shfl_down(acc, off);
  if (l == 0) scrf[512 + w] = acc;
  __syncthreads();   // bar 3
  if (t == 0) {
    float tot = ((const float*)(wsb + W_C0))[0];
#pragma unroll
    for (int g = 0; g < 8; ++g) tot += scrf[512 + g];
    out[b] = tot;
  }
}

extern "C" void kernel_launch(void* const* d_in, const int* in_sizes, int n_in,
                              void* d_out, int out_size, void* d_ws, size_t ws_size,
                              hipStream_t stream) {
  (void)in_sizes; (void)n_in; (void)out_size; (void)ws_size;
  const float* input_seq = (const float*)d_in[0];
  const float* W_emb = (const float*)d_in[1];
  const float* b_emb = (const float*)d_in[2];
  const float* W_k   = (const float*)d_in[3];
  const float* W_q   = (const float*)d_in[5];
  const float* b_q   = (const float*)d_in[6];
  const float* W_v   = (const float*)d_in[7];
  const float* b_v   = (const float*)d_in[8];
  const float* W_d   = (const float*)d_in[9];
  const float* b_d   = (const float*)d_in[10];
  char* wsb  = (char*)d_ws;
  float* out = (float*)d_out;

  pre1_kernel<<<(25152 + 255) / 256, 256, 0, stream>>>(
      W_emb, b_emb, W_k, W_q, b_q, W_v, b_v, W_d, wsb);
  pre2_kernel<<<(16705 + 255) / 256, 256, 0, stream>>>(W_d, b_d, wsb);
  main_kernel<<<Bb, TS, 0, stream>>>(input_seq, wsb, out);
}

// Round 9
// 83.585 us; speedup vs baseline: 1.0304x; 1.0304x over previous
//
#include <hip/hip_runtime.h>
#include <hip/hip_bf16.h>

typedef _Float16 half8 __attribute__((ext_vector_type(8)));
typedef _Float16 half4 __attribute__((ext_vector_type(4)));
typedef _Float16 half2v __attribute__((ext_vector_type(2)));
typedef float    f32x4 __attribute__((ext_vector_type(4)));

constexpr int Bb = 1024;
constexpr int TS = 512;   // 8 waves, 2 M-tiles per wave

// ---- workspace byte offsets ----
constexpr int W_WEV  = 0;        // f32 [64][256]  Wev[d][h]   (pre1 -> pre2 only)
constexpr int W_MTH  = 65536;    // f16 [64][256]  Mt[d][s]
constexpr int W_WEKH = 98304;    // f16 [64][64]   WekT[k][d]
constexpr int W_WEQH = 106496;   // f16 [64][64]   WeqT[k][d]
constexpr int W_BEQ  = 114688;   // f32[64]
constexpr int W_BEV  = 114944;   // f32[256]
constexpr int W_CS   = 115968;   // f32[256]
constexpr int W_CB   = 116992;   // f32[256]
constexpr int W_MS   = 118016;   // f32[64]
constexpr int W_C0   = 118272;   // f32[1]

__global__ void pre1_kernel(const float* __restrict__ W_emb, const float* __restrict__ b_emb,
                            const float* __restrict__ W_k,   const float* __restrict__ W_q,
                            const float* __restrict__ b_q,   const float* __restrict__ W_v,
                            const float* __restrict__ b_v,   const float* __restrict__ W_d,
                            char* __restrict__ wsb) {
  int i = blockIdx.x * blockDim.x + threadIdx.x;
  if (i < 16384) {                       // Wev[d][h]
    int d = i >> 8, h = i & 255;
    float a = 0.f;
#pragma unroll 8
    for (int hp = 0; hp < 256; ++hp) a += W_emb[d*256 + hp] * W_v[hp*256 + h];
    ((float*)(wsb + W_WEV))[i] = a;
  } else if (i < 20480) {                // WekT[k][d]
    int j = i - 16384; int k = j & 63, d = j >> 6;
    float a = 0.f;
#pragma unroll 8
    for (int h = 0; h < 256; ++h) a += W_emb[d*256 + h] * W_k[h*64 + k];
    ((_Float16*)(wsb + W_WEKH))[k*64 + d] = (_Float16)a;
  } else if (i < 24576) {                // WeqT[k][d]
    int j = i - 20480; int k = j & 63, d = j >> 6;
    float a = 0.f;
#pragma unroll 8
    for (int h = 0; h < 256; ++h) a += W_emb[d*256 + h] * W_q[h*64 + k];
    ((_Float16*)(wsb + W_WEQH))[k*64 + d] = (_Float16)a;
  } else if (i < 24640) {                // beq[k]
    int k = i - 24576;
    float a = b_q[k];
    for (int h = 0; h < 256; ++h) a += b_emb[h] * W_q[h*64 + k];
    ((float*)(wsb + W_BEQ))[k] = a;
  } else if (i < 24896) {                // bev[h]
    int h = i - 24640;
    float a = b_v[h];
    for (int hp = 0; hp < 256; ++hp) a += b_emb[hp] * W_v[hp*256 + h];
    ((float*)(wsb + W_BEV))[h] = a;
  } else if (i < 25152) {                // cs[h]
    int h = i - 24896;
    float a = 0.f;
    for (int s = 0; s < 256; ++s) a += W_d[s*256 + h];
    ((float*)(wsb + W_CS))[h] = a;
  }
}

__global__ void pre2_kernel(const float* __restrict__ W_d, const float* __restrict__ b_d,
                            char* __restrict__ wsb) {
  int i = blockIdx.x * blockDim.x + threadIdx.x;
  const float* wev = (const float*)(wsb + W_WEV);
  if (i < 16384) {                       // Mt[d][s] = sum_h W_d[s,h]*Wev[d,h]
    int d = i >> 8, s = i & 255;
    float a = 0.f;
#pragma unroll 8
    for (int h = 0; h < 256; ++h) a += W_d[s*256 + h] * wev[d*256 + h];
    ((_Float16*)(wsb + W_MTH))[i] = (_Float16)a;
  } else if (i < 16640) {                // cb[s]
    int s = i - 16384;
    const float* bev = (const float*)(wsb + W_BEV);
    float a = 0.f;
    for (int h = 0; h < 256; ++h) a += W_d[s*256 + h] * bev[h];
    ((float*)(wsb + W_CB))[s] = a;
  } else if (i < 16704) {                // ms[d]
    int d = i - 16640;
    const float* cs = (const float*)(wsb + W_CS);
    float a = 0.f;
    for (int h = 0; h < 256; ++h) a += wev[d*256 + h] * cs[h];
    ((float*)(wsb + W_MS))[d] = a;
  } else if (i == 16704) {               // c0
    const float* cs  = (const float*)(wsb + W_CS);
    const float* bev = (const float*)(wsb + W_BEV);
    const float* beq = (const float*)(wsb + W_BEQ);
    float cbsum = 0.f;
    for (int h = 0; h < 256; ++h) cbsum += cs[h] * bev[h];
    float bqsum = 0.f;
    for (int k = 0; k < 64; ++k) bqsum += beq[k];
    ((float*)(wsb + W_C0))[0] = b_d[0] + cbsum * bqsum;
  }
}

// LDS byte-address helpers (G4 XOR swizzle)
__device__ __forceinline__ int adrR(int r, int c) {   // QT [64][256] f16 at 0, rows 512B
  return (((r << 9) + (c << 1)) ^ ((r & 7) << 4));
}
__device__ __forceinline__ int adrU(int k, int d) {   // U  [64][64]  f16 at 32768, rows 128B
  return 32768 + (((k << 7) + (d << 1)) ^ ((k & 7) << 4));
}

#define MFMA16(A, B, C) __builtin_amdgcn_mfma_f32_16x16x32_f16((A), (B), (C), 0, 0, 0)

// One block per batch, 8 waves, wave w owns s-rows 32w..32w+31 (2 row-tiles).
// LDS: QT 32K | U 8K | scr floats at 40960: [0,512) colsum partials (col*8+w), [512,520) wave acc
// NOTE (R8 lesson): NO Bm[8] prefetch — holding it across bar1 pushed peak live regs
// past the (512,6) 85-reg cap -> 117MB scratch spill traffic. Mt loads stay inline in D.
__global__ __launch_bounds__(TS, 6) void main_kernel(const float* __restrict__ inp_g,
                                                     const char* __restrict__ wsb,
                                                     float* __restrict__ out) {
  __shared__ __align__(16) char smem[43136];
  float* scrf = (float*)(smem + 40960);

  const int b = blockIdx.x, t = threadIdx.x;
  const int l = t & 63, w = t >> 6;            // w = 0..7
  const int lhi = l >> 4, llo = l & 15;

  const float* inp = inp_g + (size_t)b * 16384;

  // ---- A-fragments of inp straight from global (used in Phase B AND Phase E) ----
  half8 Af[4];   // [tl*2+ks]: rows w*32+llo (+16*tl), d = ks*32 + lhi*8 .. +8
  {
    const int srA = w * 32 + llo;
#pragma unroll
    for (int tl = 0; tl < 2; ++tl)
#pragma unroll
      for (int ks = 0; ks < 2; ++ks) {
        const float4* p = (const float4*)(inp + (srA + tl * 16) * 64 + ks * 32 + lhi * 8);
        float4 v0 = p[0], v1 = p[1];
        half8 h;
        h[0] = (_Float16)v0.x; h[1] = (_Float16)v0.y; h[2] = (_Float16)v0.z; h[3] = (_Float16)v0.w;
        h[4] = (_Float16)v1.x; h[5] = (_Float16)v1.y; h[6] = (_Float16)v1.z; h[7] = (_Float16)v1.w;
        Af[tl * 2 + ks] = h;
      }
  }

  f32x4 zero4 = {0.f, 0.f, 0.f, 0.f};
  float acc = 0.f;
  half2v ep[2][4][2];   // packed exp(logits), C-frag coords [tl][n][(r0,r1),(r2,r3)]

  // ---- Pass 1: logits = inp @ Wek; exp (no max: bias cancels, |logit| small); colsum partials ----
  {
    f32x4 clg[2][4];
#pragma unroll
    for (int tl = 0; tl < 2; ++tl)
#pragma unroll
      for (int n = 0; n < 4; ++n) clg[tl][n] = zero4;
    const _Float16* wekh = (const _Float16*)(wsb + W_WEKH);
#pragma unroll
    for (int ks = 0; ks < 2; ++ks) {
      const int kd = ks * 32 + lhi * 8;
      half8 Bk[4];
#pragma unroll
      for (int n = 0; n < 4; ++n) Bk[n] = *(const half8*)(wekh + (n * 16 + llo) * 64 + kd);
#pragma unroll
      for (int n = 0; n < 4; ++n) {
        clg[0][n] = MFMA16(Af[ks],     Bk[n], clg[0][n]);
        clg[1][n] = MFMA16(Af[2 + ks], Bk[n], clg[1][n]);
      }
    }
#pragma unroll
    for (int n = 0; n < 4; ++n) {
      float sum = 0.f;
      float ev[2][4];
#pragma unroll
      for (int tl = 0; tl < 2; ++tl)
#pragma unroll
        for (int r = 0; r < 4; ++r) { ev[tl][r] = __expf(clg[tl][n][r]); sum += ev[tl][r]; }
#pragma unroll
      for (int tl = 0; tl < 2; ++tl) {
        half2v p0, p1;
        p0[0] = (_Float16)ev[tl][0]; p0[1] = (_Float16)ev[tl][1];
        p1[0] = (_Float16)ev[tl][2]; p1[1] = (_Float16)ev[tl][3];
        ep[tl][n][0] = p0; ep[tl][n][1] = p1;
      }
      sum += __shfl_xor(sum, 16);
      sum += __shfl_xor(sum, 32);
      if (lhi == 0) scrf[(n * 16 + llo) * 8 + w] = sum;
    }
  }

  // ---- Pass 2: Q = inp @ Weq -> QT (f16, LDS) + cb-term (kills cq) ----
  {
    f32x4 cq[2][4];
#pragma unroll
    for (int tl = 0; tl < 2; ++tl)
#pragma unroll
      for (int n = 0; n < 4; ++n) cq[tl][n] = zero4;
    const _Float16* weqh = (const _Float16*)(wsb + W_WEQH);
#pragma unroll
    for (int ks = 0; ks < 2; ++ks) {
      const int kd = ks * 32 + lhi * 8;
      half8 Bq[4];
#pragma unroll
      for (int n = 0; n < 4; ++n) Bq[n] = *(const half8*)(weqh + (n * 16 + llo) * 64 + kd);
#pragma unroll
      for (int n = 0; n < 4; ++n) {
        cq[0][n] = MFMA16(Af[ks],     Bq[n], cq[0][n]);
        cq[1][n] = MFMA16(Af[2 + ks], Bq[n], cq[1][n]);
      }
    }
#pragma unroll
    for (int tl = 0; tl < 2; ++tl) {
      int sbase = w * 32 + tl * 16 + lhi * 4;
#pragma unroll
      for (int n = 0; n < 4; ++n) {
        half4 qh;
#pragma unroll
        for (int r = 0; r < 4; ++r) qh[r] = (_Float16)cq[tl][n][r];
        *(half4*)(smem + adrR(n * 16 + llo, sbase)) = qh;
      }
    }
    const float* cb = (const float*)(wsb + W_CB);
#pragma unroll
    for (int tl = 0; tl < 2; ++tl)
#pragma unroll
      for (int r = 0; r < 4; ++r) {
        float qs = (cq[tl][0][r] + cq[tl][1][r]) + (cq[tl][2][r] + cq[tl][3][r]);
        acc += cb[w * 32 + tl * 16 + lhi * 4 + r] * qs;
      }
  }
  __syncthreads();   // bar 1: QT + colsum partials visible

  // ---- Phase D: T = QT x Mt (K=256), Mt loaded inline (L2-hot); U -> LDS f16 ----
  const int d0 = (w & 3) * 16;
  const int ka = (w >> 2) * 16, kb = ka + 32;
  {
    const _Float16* mth = (const _Float16*)(wsb + W_MTH);
    f32x4 cta = zero4, ctb = zero4;
#pragma unroll
    for (int ks = 0; ks < 8; ++ks) {
      const int kd = ks * 32 + lhi * 8;
      half8 Bm  = *(const half8*)(mth + (d0 + llo) * 256 + kd);
      half8 Aqa = *(const half8*)(smem + adrR(ka + llo, kd));
      half8 Aqb = *(const half8*)(smem + adrR(kb + llo, kd));
      cta = MFMA16(Aqa, Bm, cta);
      ctb = MFMA16(Aqb, Bm, ctb);
    }
    const float* beq = (const float*)(wsb + W_BEQ);
    const float* msv = (const float*)(wsb + W_MS);
    float msd = msv[d0 + llo];
#pragma unroll
    for (int r = 0; r < 4; ++r) {
      float Uva = cta[r] + beq[ka + lhi * 4 + r] * msd;
      *(_Float16*)(smem + adrU(ka + lhi * 4 + r, d0 + llo)) = (_Float16)Uva;
      float Uvb = ctb[r] + beq[kb + lhi * 4 + r] * msd;
      *(_Float16*)(smem + adrU(kb + lhi * 4 + r, d0 + llo)) = (_Float16)Uvb;
    }
  }
  __syncthreads();   // bar 2: U visible

  // ---- Phase E: G = inp @ U^T (reuses Af); acc += sum e*cg / colsum ----
  {
    f32x4 cga[4], cgb[4];
#pragma unroll
    for (int n = 0; n < 4; ++n) { cga[n] = zero4; cgb[n] = zero4; }
#pragma unroll
    for (int ks = 0; ks < 2; ++ks) {
      const int kd = ks * 32 + lhi * 8;
      half8 Bu[4];
#pragma unroll
      for (int n = 0; n < 4; ++n) Bu[n] = *(const half8*)(smem + adrU(n * 16 + llo, kd));
#pragma unroll
      for (int n = 0; n < 4; ++n) {
        cga[n] = MFMA16(Af[ks],     Bu[n], cga[n]);
        cgb[n] = MFMA16(Af[2 + ks], Bu[n], cgb[n]);
      }
    }
#pragma unroll
    for (int n = 0; n < 4; ++n) {
      const float4* cp = (const float4*)(scrf + (n * 16 + llo) * 8);
      float4 c0v = cp[0], c1v = cp[1];
      float ss = ((c0v.x + c0v.y) + (c0v.z + c0v.w)) + ((c1v.x + c1v.y) + (c1v.z + c1v.w));
      float rs = __builtin_amdgcn_rcpf(ss);
      float dot = 0.f;
#pragma unroll
      for (int r = 0; r < 4; ++r) {
        float ea = (float)ep[0][n][r >> 1][r & 1];
        float eb = (float)ep[1][n][r >> 1][r & 1];
        dot += ea * cga[n][r] + eb * cgb[n][r];
      }
      acc += dot * rs;
    }
  }

  // ---- block reduction ----
#pragma unroll
  for (int off = 32; off; off >>= 1) acc += __shfl_down(acc, off);
  if (l == 0) scrf[512 + w] = acc;
  __syncthreads();   // bar 3
  if (t == 0) {
    float tot = ((const float*)(wsb + W_C0))[0];
#pragma unroll
    for (int g = 0; g < 8; ++g) tot += scrf[512 + g];
    out[b] = tot;
  }
}

extern "C" void kernel_launch(void* const* d_in, const int* in_sizes, int n_in,
                              void* d_out, int out_size, void* d_ws, size_t ws_size,
                              hipStream_t stream) {
  (void)in_sizes; (void)n_in; (void)out_size; (void)ws_size;
  const float* input_seq = (const float*)d_in[0];
  const float* W_emb = (const float*)d_in[1];
  const float* b_emb = (const float*)d_in[2];
  const float* W_k   = (const float*)d_in[3];
  const float* W_q   = (const float*)d_in[5];
  const float* b_q   = (const float*)d_in[6];
  const float* W_v   = (const float*)d_in[7];
  const float* b_v   = (const float*)d_in[8];
  const float* W_d   = (const float*)d_in[9];
  const float* b_d   = (const float*)d_in[10];
  char* wsb  = (char*)d_ws;
  float* out = (float*)d_out;

  pre1_kernel<<<(25152 + 255) / 256, 256, 0, stream>>>(
      W_emb, b_emb, W_k, W_q, b_q, W_v, b_v, W_d, wsb);
  pre2_kernel<<<(16705 + 255) / 256, 256, 0, stream>>>(W_d, b_d, wsb);
  main_kernel<<<Bb, TS, 0, stream>>>(input_seq, wsb, out);
}

// Round 10
// 62.522 us; speedup vs baseline: 1.3775x; 1.3369x over previous
//
#include <hip/hip_runtime.h>
#include <hip/hip_bf16.h>

typedef _Float16 half8 __attribute__((ext_vector_type(8)));
typedef _Float16 half4 __attribute__((ext_vector_type(4)));
typedef _Float16 half2v __attribute__((ext_vector_type(2)));
typedef float    f32x4 __attribute__((ext_vector_type(4)));

constexpr int Bb = 1024;
constexpr int TS = 512;   // 8 waves, 2 M-tiles per wave

// ---- workspace byte offsets ----
constexpr int W_WEV  = 0;        // f32 [64][256]  Wev[d][h]   (pre1 -> pre2 only)
constexpr int W_MTH  = 65536;    // f16 [64][256]  Mt[d][s]
constexpr int W_WEKH = 98304;    // f16 [64][64]   WekT[k][d]
constexpr int W_WEQH = 106496;   // f16 [64][64]   WeqT[k][d]
constexpr int W_BEQ  = 114688;   // f32[64]
constexpr int W_BEV  = 114944;   // f32[256]
constexpr int W_CS   = 115968;   // f32[256]
constexpr int W_CB   = 116992;   // f32[256]
constexpr int W_MS   = 118016;   // f32[64]
constexpr int W_C0   = 118272;   // f32[1]

__global__ void pre1_kernel(const float* __restrict__ W_emb, const float* __restrict__ b_emb,
                            const float* __restrict__ W_k,   const float* __restrict__ W_q,
                            const float* __restrict__ b_q,   const float* __restrict__ W_v,
                            const float* __restrict__ b_v,   const float* __restrict__ W_d,
                            char* __restrict__ wsb) {
  int i = blockIdx.x * blockDim.x + threadIdx.x;
  if (i < 16384) {                       // Wev[d][h]
    int d = i >> 8, h = i & 255;
    float a = 0.f;
#pragma unroll 8
    for (int hp = 0; hp < 256; ++hp) a += W_emb[d*256 + hp] * W_v[hp*256 + h];
    ((float*)(wsb + W_WEV))[i] = a;
  } else if (i < 20480) {                // WekT[k][d]
    int j = i - 16384; int k = j & 63, d = j >> 6;
    float a = 0.f;
#pragma unroll 8
    for (int h = 0; h < 256; ++h) a += W_emb[d*256 + h] * W_k[h*64 + k];
    ((_Float16*)(wsb + W_WEKH))[k*64 + d] = (_Float16)a;
  } else if (i < 24576) {                // WeqT[k][d]
    int j = i - 20480; int k = j & 63, d = j >> 6;
    float a = 0.f;
#pragma unroll 8
    for (int h = 0; h < 256; ++h) a += W_emb[d*256 + h] * W_q[h*64 + k];
    ((_Float16*)(wsb + W_WEQH))[k*64 + d] = (_Float16)a;
  } else if (i < 24640) {                // beq[k]
    int k = i - 24576;
    float a = b_q[k];
    for (int h = 0; h < 256; ++h) a += b_emb[h] * W_q[h*64 + k];
    ((float*)(wsb + W_BEQ))[k] = a;
  } else if (i < 24896) {                // bev[h]
    int h = i - 24640;
    float a = b_v[h];
    for (int hp = 0; hp < 256; ++hp) a += b_emb[hp] * W_v[hp*256 + h];
    ((float*)(wsb + W_BEV))[h] = a;
  } else if (i < 25152) {                // cs[h]
    int h = i - 24896;
    float a = 0.f;
    for (int s = 0; s < 256; ++s) a += W_d[s*256 + h];
    ((float*)(wsb + W_CS))[h] = a;
  }
}

__global__ void pre2_kernel(const float* __restrict__ W_d, const float* __restrict__ b_d,
                            char* __restrict__ wsb) {
  int i = blockIdx.x * blockDim.x + threadIdx.x;
  const float* wev = (const float*)(wsb + W_WEV);
  if (i < 16384) {                       // Mt[d][s] = sum_h W_d[s,h]*Wev[d,h]
    int d = i >> 8, s = i & 255;
    float a = 0.f;
#pragma unroll 8
    for (int h = 0; h < 256; ++h) a += W_d[s*256 + h] * wev[d*256 + h];
    ((_Float16*)(wsb + W_MTH))[i] = (_Float16)a;
  } else if (i < 16640) {                // cb[s]
    int s = i - 16384;
    const float* bev = (const float*)(wsb + W_BEV);
    float a = 0.f;
    for (int h = 0; h < 256; ++h) a += W_d[s*256 + h] * bev[h];
    ((float*)(wsb + W_CB))[s] = a;
  } else if (i < 16704) {                // ms[d]
    int d = i - 16640;
    const float* cs = (const float*)(wsb + W_CS);
    float a = 0.f;
    for (int h = 0; h < 256; ++h) a += wev[d*256 + h] * cs[h];
    ((float*)(wsb + W_MS))[d] = a;
  } else if (i == 16704) {               // c0
    const float* cs  = (const float*)(wsb + W_CS);
    const float* bev = (const float*)(wsb + W_BEV);
    const float* beq = (const float*)(wsb + W_BEQ);
    float cbsum = 0.f;
    for (int h = 0; h < 256; ++h) cbsum += cs[h] * bev[h];
    float bqsum = 0.f;
    for (int k = 0; k < 64; ++k) bqsum += beq[k];
    ((float*)(wsb + W_C0))[0] = b_d[0] + cbsum * bqsum;
  }
}

// LDS byte-address helpers (G4 XOR swizzle)
__device__ __forceinline__ int adrR(int r, int c) {   // QT [64][256] f16 at 0, rows 512B
  return (((r << 9) + (c << 1)) ^ ((r & 7) << 4));
}
__device__ __forceinline__ int adrU(int k, int d) {   // U  [64][64]  f16 at 32768, rows 128B
  return 32768 + (((k << 7) + (d << 1)) ^ ((k & 7) << 4));
}

#define MFMA16(A, B, C) __builtin_amdgcn_mfma_f32_16x16x32_f16((A), (B), (C), 0, 0, 0)

// One block per batch, 8 waves, wave w owns s-rows 32w..32w+31 (2 row-tiles).
// LDS: QT 32K | U 8K | scr floats at 40960: [0,512) colsum partials (col*8+w), [512,520) wave acc
// REGISTER BUDGET (R8/R9 lesson): peak live ~80-85 regs (Pass2: cq32+Af16+ep8+Bq16+addr).
// A 6-waves/EU cap (85 regs) made the allocator collapse to 40 regs + ~110MB wholesale
// scratch spill. (512,4) -> 128-reg budget, 2 blocks/CU: spill-free beats +1 block resident.
__global__ __launch_bounds__(TS, 4) void main_kernel(const float* __restrict__ inp_g,
                                                     const char* __restrict__ wsb,
                                                     float* __restrict__ out) {
  __shared__ __align__(16) char smem[43136];
  float* scrf = (float*)(smem + 40960);

  const int b = blockIdx.x, t = threadIdx.x;
  const int l = t & 63, w = t >> 6;            // w = 0..7
  const int lhi = l >> 4, llo = l & 15;

  const float* inp = inp_g + (size_t)b * 16384;

  // ---- A-fragments of inp straight from global (used in Phase B AND Phase E) ----
  half8 Af[4];   // [tl*2+ks]: rows w*32+llo (+16*tl), d = ks*32 + lhi*8 .. +8
  {
    const int srA = w * 32 + llo;
#pragma unroll
    for (int tl = 0; tl < 2; ++tl)
#pragma unroll
      for (int ks = 0; ks < 2; ++ks) {
        const float4* p = (const float4*)(inp + (srA + tl * 16) * 64 + ks * 32 + lhi * 8);
        float4 v0 = p[0], v1 = p[1];
        half8 h;
        h[0] = (_Float16)v0.x; h[1] = (_Float16)v0.y; h[2] = (_Float16)v0.z; h[3] = (_Float16)v0.w;
        h[4] = (_Float16)v1.x; h[5] = (_Float16)v1.y; h[6] = (_Float16)v1.z; h[7] = (_Float16)v1.w;
        Af[tl * 2 + ks] = h;
      }
  }

  f32x4 zero4 = {0.f, 0.f, 0.f, 0.f};
  float acc = 0.f;
  half2v ep[2][4][2];   // packed exp(logits), C-frag coords [tl][n][(r0,r1),(r2,r3)]

  // ---- Pass 1: logits = inp @ Wek; exp (no max: bias cancels, |logit| small); colsum partials ----
  {
    f32x4 clg[2][4];
#pragma unroll
    for (int tl = 0; tl < 2; ++tl)
#pragma unroll
      for (int n = 0; n < 4; ++n) clg[tl][n] = zero4;
    const _Float16* wekh = (const _Float16*)(wsb + W_WEKH);
#pragma unroll
    for (int ks = 0; ks < 2; ++ks) {
      const int kd = ks * 32 + lhi * 8;
      half8 Bk[4];
#pragma unroll
      for (int n = 0; n < 4; ++n) Bk[n] = *(const half8*)(wekh + (n * 16 + llo) * 64 + kd);
#pragma unroll
      for (int n = 0; n < 4; ++n) {
        clg[0][n] = MFMA16(Af[ks],     Bk[n], clg[0][n]);
        clg[1][n] = MFMA16(Af[2 + ks], Bk[n], clg[1][n]);
      }
    }
#pragma unroll
    for (int n = 0; n < 4; ++n) {
      float sum = 0.f;
      float ev[2][4];
#pragma unroll
      for (int tl = 0; tl < 2; ++tl)
#pragma unroll
        for (int r = 0; r < 4; ++r) { ev[tl][r] = __expf(clg[tl][n][r]); sum += ev[tl][r]; }
#pragma unroll
      for (int tl = 0; tl < 2; ++tl) {
        half2v p0, p1;
        p0[0] = (_Float16)ev[tl][0]; p0[1] = (_Float16)ev[tl][1];
        p1[0] = (_Float16)ev[tl][2]; p1[1] = (_Float16)ev[tl][3];
        ep[tl][n][0] = p0; ep[tl][n][1] = p1;
      }
      sum += __shfl_xor(sum, 16);
      sum += __shfl_xor(sum, 32);
      if (lhi == 0) scrf[(n * 16 + llo) * 8 + w] = sum;
    }
  }

  // ---- Pass 2: Q = inp @ Weq -> QT (f16, LDS) + cb-term (kills cq) ----
  {
    f32x4 cq[2][4];
#pragma unroll
    for (int tl = 0; tl < 2; ++tl)
#pragma unroll
      for (int n = 0; n < 4; ++n) cq[tl][n] = zero4;
    const _Float16* weqh = (const _Float16*)(wsb + W_WEQH);
#pragma unroll
    for (int ks = 0; ks < 2; ++ks) {
      const int kd = ks * 32 + lhi * 8;
      half8 Bq[4];
#pragma unroll
      for (int n = 0; n < 4; ++n) Bq[n] = *(const half8*)(weqh + (n * 16 + llo) * 64 + kd);
#pragma unroll
      for (int n = 0; n < 4; ++n) {
        cq[0][n] = MFMA16(Af[ks],     Bq[n], cq[0][n]);
        cq[1][n] = MFMA16(Af[2 + ks], Bq[n], cq[1][n]);
      }
    }
#pragma unroll
    for (int tl = 0; tl < 2; ++tl) {
      int sbase = w * 32 + tl * 16 + lhi * 4;
#pragma unroll
      for (int n = 0; n < 4; ++n) {
        half4 qh;
#pragma unroll
        for (int r = 0; r < 4; ++r) qh[r] = (_Float16)cq[tl][n][r];
        *(half4*)(smem + adrR(n * 16 + llo, sbase)) = qh;
      }
    }
    const float* cb = (const float*)(wsb + W_CB);
#pragma unroll
    for (int tl = 0; tl < 2; ++tl)
#pragma unroll
      for (int r = 0; r < 4; ++r) {
        float qs = (cq[tl][0][r] + cq[tl][1][r]) + (cq[tl][2][r] + cq[tl][3][r]);
        acc += cb[w * 32 + tl * 16 + lhi * 4 + r] * qs;
      }
  }
  __syncthreads();   // bar 1: QT + colsum partials visible

  // ---- Phase D: T = QT x Mt (K=256), Mt loaded inline (L2-hot); U -> LDS f16 ----
  const int d0 = (w & 3) * 16;
  const int ka = (w >> 2) * 16, kb = ka + 32;
  {
    const _Float16* mth = (const _Float16*)(wsb + W_MTH);
    f32x4 cta = zero4, ctb = zero4;
#pragma unroll
    for (int ks = 0; ks < 8; ++ks) {
      const int kd = ks * 32 + lhi * 8;
      half8 Bm  = *(const half8*)(mth + (d0 + llo) * 256 + kd);
      half8 Aqa = *(const half8*)(smem + adrR(ka + llo, kd));
      half8 Aqb = *(const half8*)(smem + adrR(kb + llo, kd));
      cta = MFMA16(Aqa, Bm, cta);
      ctb = MFMA16(Aqb, Bm, ctb);
    }
    const float* beq = (const float*)(wsb + W_BEQ);
    const float* msv = (const float*)(wsb + W_MS);
    float msd = msv[d0 + llo];
#pragma unroll
    for (int r = 0; r < 4; ++r) {
      float Uva = cta[r] + beq[ka + lhi * 4 + r] * msd;
      *(_Float16*)(smem + adrU(ka + lhi * 4 + r, d0 + llo)) = (_Float16)Uva;
      float Uvb = ctb[r] + beq[kb + lhi * 4 + r] * msd;
      *(_Float16*)(smem + adrU(kb + lhi * 4 + r, d0 + llo)) = (_Float16)Uvb;
    }
  }
  __syncthreads();   // bar 2: U visible

  // ---- Phase E: G = inp @ U^T (reuses Af); acc += sum e*cg / colsum ----
  {
    f32x4 cga[4], cgb[4];
#pragma unroll
    for (int n = 0; n < 4; ++n) { cga[n] = zero4; cgb[n] = zero4; }
#pragma unroll
    for (int ks = 0; ks < 2; ++ks) {
      const int kd = ks * 32 + lhi * 8;
      half8 Bu[4];
#pragma unroll
      for (int n = 0; n < 4; ++n) Bu[n] = *(const half8*)(smem + adrU(n * 16 + llo, kd));
#pragma unroll
      for (int n = 0; n < 4; ++n) {
        cga[n] = MFMA16(Af[ks],     Bu[n], cga[n]);
        cgb[n] = MFMA16(Af[2 + ks], Bu[n], cgb[n]);
      }
    }
#pragma unroll
    for (int n = 0; n < 4; ++n) {
      const float4* cp = (const float4*)(scrf + (n * 16 + llo) * 8);
      float4 c0v = cp[0], c1v = cp[1];
      float ss = ((c0v.x + c0v.y) + (c0v.z + c0v.w)) + ((c1v.x + c1v.y) + (c1v.z + c1v.w));
      float rs = __builtin_amdgcn_rcpf(ss);
      float dot = 0.f;
#pragma unroll
      for (int r = 0; r < 4; ++r) {
        float ea = (float)ep[0][n][r >> 1][r & 1];
        float eb = (float)ep[1][n][r >> 1][r & 1];
        dot += ea * cga[n][r] + eb * cgb[n][r];
      }
      acc += dot * rs;
    }
  }

  // ---- block reduction ----
#pragma unroll
  for (int off = 32; off; off >>= 1) acc += __shfl_down(acc, off);
  if (l == 0) scrf[512 + w] = acc;
  __syncthreads();   // bar 3
  if (t == 0) {
    float tot = ((const float*)(wsb + W_C0))[0];
#pragma unroll
    for (int g = 0; g < 8; ++g) tot += scrf[512 + g];
    out[b] = tot;
  }
}

extern "C" void kernel_launch(void* const* d_in, const int* in_sizes, int n_in,
                              void* d_out, int out_size, void* d_ws, size_t ws_size,
                              hipStream_t stream) {
  (void)in_sizes; (void)n_in; (void)out_size; (void)ws_size;
  const float* input_seq = (const float*)d_in[0];
  const float* W_emb = (const float*)d_in[1];
  const float* b_emb = (const float*)d_in[2];
  const float* W_k   = (const float*)d_in[3];
  const float* W_q   = (const float*)d_in[5];
  const float* b_q   = (const float*)d_in[6];
  const float* W_v   = (const float*)d_in[7];
  const float* b_v   = (const float*)d_in[8];
  const float* W_d   = (const float*)d_in[9];
  const float* b_d   = (const float*)d_in[10];
  char* wsb  = (char*)d_ws;
  float* out = (float*)d_out;

  pre1_kernel<<<(25152 + 255) / 256, 256, 0, stream>>>(
      W_emb, b_emb, W_k, W_q, b_q, W_v, b_v, W_d, wsb);
  pre2_kernel<<<(16705 + 255) / 256, 256, 0, stream>>>(W_d, b_d, wsb);
  main_kernel<<<Bb, TS, 0, stream>>>(input_seq, wsb, out);
}